// Round 7
// baseline (334.304 us; speedup 1.0000x reference)
//
#include <hip/hip_runtime.h>

// out = softmax(q @ keys^T) @ keys, fused flash-style, round 7.
// = r6 (32 q/wave, split-K across wave pairs, end-of-kernel flash-combine,
//   2-way score swizzle) + restored r5-style overlap: KVB=16 so each split
//   double-buffers (2 x 16KB), DMA for tile t+1 issued before compute of t,
//   ONE barrier per tile (drains vmcnt). PV on x16 (no key permutation);
//   KT-16 image packed [d>>3][g][d&7] -> b64 PV reads 2-way conflict-free.

typedef _Float16 f16;
typedef f16 f16x8 __attribute__((ext_vector_type(8)));
typedef f16 f16x4 __attribute__((ext_vector_type(4)));
typedef float f32x4 __attribute__((ext_vector_type(4)));

#define MF32(a, b, c) __builtin_amdgcn_mfma_f32_16x16x32_f16(a, b, c, 0, 0, 0)
#define MF16(a, b, c) __builtin_amdgcn_mfma_f32_16x16x16f16(a, b, c, 0, 0, 0)

__device__ __forceinline__ void gl_lds16(const f16* g, f16* l) {
  __builtin_amdgcn_global_load_lds(
      (const __attribute__((address_space(1))) void*)g,
      (__attribute__((address_space(3))) void*)l, 16, 0, 0);
}

// ---- pre-kernel: swizzled per-16-key-tile images (grid 256 x 256) ----
// ws f16 layout: [0, 524288): Kh images, 128 tiles x 4096;
//                [524288, 1048576): KT images, 128 tiles x 4096.
__global__ void prep_kernel(const float* __restrict__ keys, f16* __restrict__ ws) {
  int i = blockIdx.x * 256 + threadIdx.x;  // 0..65535
  {  // Kh: tile t, key kk (0..15), chunk c (8 f16); slot = c ^ (kk&7)
    int t = i >> 9, kk = (i >> 5) & 15, c = i & 31;
    const float* src = keys + (((t << 4) + kk) << 8) + (c << 3);
    f16x8 v;
    #pragma unroll
    for (int e = 0; e < 8; ++e) v[e] = (f16)src[e];
    *(f16x8*)&ws[t * 4096 + kk * 256 + ((c ^ (kk & 7)) << 3)] = v;
  }
  #pragma unroll
  for (int r = 0; r < 2; ++r) {  // KT: 2 f16x4 stores per thread
    int j = i * 2 + r;           // 0..131071
    int t = j >> 10, d = (j >> 2) & 255, gg = j & 3;
    const float* src = keys + (((t << 4) + (gg << 2)) << 8) + d;
    f16x4 v;
    #pragma unroll
    for (int e = 0; e < 4; ++e) v[e] = (f16)src[e << 8];
    *(f16x4*)&ws[524288 + t * 4096 + ((d >> 3) << 7) + (gg << 5) + ((d & 7) << 2)] = v;
  }
}

#define STORE_HALF(DTB)                                                     \
  {                                                                         \
    _Pragma("unroll") for (int j = 0; j < 16; ++j) {                        \
      const int dt = (DTB) + (j >> 1);                                      \
      const int grp = j & 1;                                                \
      f32x4 pv = *(const f32x4*)(rdp + (((j + lane) & 15) << 4));           \
      f32x4 ow = grp ? O1[dt] : O0[dt];                                     \
      float4 w4;                                                            \
      w4.x = (ow[0] * A_[grp][0] + pv[0] * B_[grp][0]) * N_[grp][0];        \
      w4.y = (ow[1] * A_[grp][1] + pv[1] * B_[grp][1]) * N_[grp][1];        \
      w4.z = (ow[2] * A_[grp][2] + pv[2] * B_[grp][2]) * N_[grp][2];        \
      w4.w = (ow[3] * A_[grp][3] + pv[3] * B_[grp][3]) * N_[grp][3];        \
      int c = dt * 16 + qr;                                                 \
      *(float4*)(ob + ((size_t)c << 12) + grp * 16) = w4;                   \
    }                                                                       \
  }

__global__ __launch_bounds__(256, 2)
void mtr_kernel(const f16* __restrict__ ws,
                const float* __restrict__ query,
                float* __restrict__ out) {
  // f16 idx: split s base s*16384; buffer b: +b*8192; Kh +0 (4096), KT +4096
  __shared__ f16 SH[32768];            // 64 KB
  __shared__ float ML[2][2][64][4];    // 4 KB

  const int tid  = threadIdx.x;
  const int lane = tid & 63;
  const int wave = tid >> 6;   // 0..3
  const int p    = wave >> 1;  // q-pair: rows [p*32, p*32+32)
  const int s    = wave & 1;   // tile-split: 16-key tiles [s*64, s*64+64)
  const int g    = lane >> 4;  // 0..3
  const int qr   = lane & 15;

  const int nbase  = blockIdx.x * 64;
  const int b      = nbase >> 12;
  const int hwbase = nbase & 4095;

  // ---- q fragments, 2 groups of 16 rows, hi/lo fp16 split (q exact).
  f16x8 qh0[8], ql0[8], qh1[8], ql1[8];
  #pragma unroll
  for (int grp = 0; grp < 2; ++grp) {
    const float* qb = query + ((size_t)b << 20) + hwbase + p * 32 + grp * 16 + qr;
    #pragma unroll
    for (int dt = 0; dt < 8; ++dt)
      #pragma unroll
      for (int j = 0; j < 8; ++j) {
        int c = dt * 32 + g * 8 + j;
        float v = qb[(size_t)c << 12];
        f16 h = (f16)v;
        if (grp == 0) { qh0[dt][j] = h; ql0[dt][j] = (f16)(v - (float)h); }
        else          { qh1[dt][j] = h; ql1[dt][j] = (f16)(v - (float)h); }
      }
  }

  f32x4 O0[16], O1[16];
  #pragma unroll
  for (int i = 0; i < 16; ++i) {
    O0[i] = (f32x4){0.f, 0.f, 0.f, 0.f};
    O1[i] = (f32x4){0.f, 0.f, 0.f, 0.f};
  }
  float m0 = -INFINITY, l0 = 0.f, m1 = -INFINITY, l1 = 0.f;

  const int xs  = qr & 7;                       // score chunk swizzle
  const int rbS = qr * 256;                     // score A row base (f16)
  const int rT  = ((qr >> 3) << 7) + (g << 5) + ((qr & 7) << 2);  // KT base

  // staging: wave(p,s): p=0 -> Kh, p=1 -> KT of split s; 8 x 1KB per tile
  const f16* wsbase = ws + (p ? 524288 : 0) + lane * 8;
  f16* sbase = &SH[s * 16384 + (p ? 4096 : 0)];

  {  // prologue: stage tile s*64 into buffer 0
    const f16* sp = wsbase + (s * 64) * 4096;
    #pragma unroll
    for (int i = 0; i < 8; ++i) gl_lds16(sp + i * 512, sbase + i * 512);
  }
  __syncthreads();

  for (int tl = 0; tl < 64; ++tl) {
    const int cur = tl & 1;

    // ---- issue DMA for tile tl+1 into other buffer (overlaps compute)
    if (tl + 1 < 64) {
      const f16* sp = wsbase + (s * 64 + tl + 1) * 4096;
      f16* dst = sbase + (cur ^ 1) * 8192;
      #pragma unroll
      for (int i = 0; i < 8; ++i) gl_lds16(sp + i * 512, dst + i * 512);
    }

    const f16* KBc = &SH[s * 16384 + cur * 8192];
    const f16* KTc = KBc + 4096;

    // ---- score: S^T[16 keys][16 q] per group; A-frags shared
    f32x4 s00 = (f32x4){0.f, 0.f, 0.f, 0.f};
    f32x4 s01 = (f32x4){0.f, 0.f, 0.f, 0.f};
    #pragma unroll
    for (int dt = 0; dt < 8; ++dt) {
      f16x8 a0 = *(const f16x8*)&KBc[rbS + ((((dt << 2) + g) ^ xs) << 3)];
      s00 = MF32(a0, qh0[dt], s00); s00 = MF32(a0, ql0[dt], s00);
      s01 = MF32(a0, qh1[dt], s01); s01 = MF32(a0, ql1[dt], s01);
    }
    // lane holds S[key g*4+i][q qr] per group

    // ---- online softmax per group; pa = x16 PV A-frag directly
    f16x4 pa0, pa1;
    #pragma unroll
    for (int grp = 0; grp < 2; ++grp) {
      f32x4& sa = grp ? s01 : s00;
      float& mr = grp ? m1 : m0;
      float& lr = grp ? l1 : l0;
      float tmax = fmaxf(fmaxf(sa[0], sa[1]), fmaxf(sa[2], sa[3]));
      tmax = fmaxf(tmax, __shfl_xor(tmax, 16));
      tmax = fmaxf(tmax, __shfl_xor(tmax, 32));
      if (__any(tmax > mr + 8.f)) {  // defer-max (T13)
        float m_new = fmaxf(mr, tmax);
        float sc = __expf(mr - m_new);
        lr *= sc;
        mr = m_new;
        float osc0 = __shfl(sc, g * 4 + 0);
        float osc1 = __shfl(sc, g * 4 + 1);
        float osc2 = __shfl(sc, g * 4 + 2);
        float osc3 = __shfl(sc, g * 4 + 3);
        f32x4* O = grp ? O1 : O0;
        #pragma unroll
        for (int dtile = 0; dtile < 16; ++dtile) {
          O[dtile][0] *= osc0; O[dtile][1] *= osc1;
          O[dtile][2] *= osc2; O[dtile][3] *= osc3;
        }
      }
      float ts = 0.f;
      f16x4& pa = grp ? pa1 : pa0;
      #pragma unroll
      for (int i = 0; i < 4; ++i) {
        float e = __expf(sa[i] - mr);
        ts += e;
        pa[i] = (f16)e;
      }
      ts += __shfl_xor(ts, 16);
      ts += __shfl_xor(ts, 32);
      lr += ts;
    }

    // ---- PV: x16, B-frag b64 from KT image (2-way pattern), shared by groups
    #pragma unroll
    for (int dtile = 0; dtile < 16; ++dtile) {
      f16x4 vb = *(const f16x4*)&KTc[dtile * 256 + rT];
      O0[dtile] = MF16(pa0, vb, O0[dtile]);
      O1[dtile] = MF16(pa1, vb, O1[dtile]);
    }

    __syncthreads();  // drains vmcnt(0): next buffer staged; cur free to overwrite
  }

  // ---------- flash-combine across splits (through dead tile buffers) ----------
  char* pairR = (char*)SH + p * 32768;
  {
    char* wrp = pairR + s * 16384 + lane * 256;
    if (s == 0) {
      #pragma unroll
      for (int j = 0; j < 16; ++j) {
        f32x4 ow = (j & 1) ? O1[8 + (j >> 1)] : O0[8 + (j >> 1)];
        *(f32x4*)(wrp + (((j + lane) & 15) << 4)) = ow;
      }
    } else {
      #pragma unroll
      for (int j = 0; j < 16; ++j) {
        f32x4 ow = (j & 1) ? O1[j >> 1] : O0[j >> 1];
        *(f32x4*)(wrp + (((j + lane) & 15) << 4)) = ow;
      }
    }
    ML[p][s][lane][0] = m0; ML[p][s][lane][1] = l0;
    ML[p][s][lane][2] = m1; ML[p][s][lane][3] = l1;
  }
  __syncthreads();

  float A_[2][4], B_[2][4], N_[2][4];
  {
    float mo0 = ML[p][s ^ 1][lane][0], lo0 = ML[p][s ^ 1][lane][1];
    float mo1 = ML[p][s ^ 1][lane][2], lo1 = ML[p][s ^ 1][lane][3];
    float ms0 = fmaxf(m0, mo0);
    float al0 = __expf(m0 - ms0), be0 = __expf(mo0 - ms0);
    float ivl0 = 1.f / (l0 * al0 + lo0 * be0);
    float ms1 = fmaxf(m1, mo1);
    float al1 = __expf(m1 - ms1), be1 = __expf(mo1 - ms1);
    float ivl1 = 1.f / (l1 * al1 + lo1 * be1);
    #pragma unroll
    for (int i = 0; i < 4; ++i) {
      A_[0][i] = __shfl(al0, g * 4 + i);
      B_[0][i] = __shfl(be0, g * 4 + i);
      N_[0][i] = __shfl(ivl0, g * 4 + i);
      A_[1][i] = __shfl(al1, g * 4 + i);
      B_[1][i] = __shfl(be1, g * 4 + i);
      N_[1][i] = __shfl(ivl1, g * 4 + i);
    }
  }
  const char* rdp = pairR + (s ^ 1) * 16384 + lane * 256;
  float* ob = out + ((size_t)b << 20) + hwbase + p * 32 + g * 4;
  if (s == 0) STORE_HALF(0) else STORE_HALF(8)
}

extern "C" void kernel_launch(void* const* d_in, const int* in_sizes, int n_in,
                              void* d_out, int out_size, void* d_ws, size_t ws_size,
                              hipStream_t stream) {
  const float* keys  = (const float*)d_in[0];
  const float* query = (const float*)d_in[1];
  float* out = (float*)d_out;
  f16* ws = (f16*)d_ws;
  hipLaunchKernelGGL(prep_kernel, dim3(256), dim3(256), 0, stream, keys, ws);
  hipLaunchKernelGGL(mtr_kernel, dim3(512), dim3(256), 0, stream, ws, query, out);
}

// Round 8
// 125.282 us; speedup vs baseline: 2.6684x; 2.6684x over previous
//
#include <hip/hip_runtime.h>

// out = softmax(q @ keys^T) @ keys, fused flash-style, round 8.
// = r5 (best measured: 133us) + the r6-VALIDATED score-read bank swizzle:
//   Kh image slot = c ^ ((kk&3)|(((kk>>3)&1)<<2))  -> read xor
//   xs = (qr&3)|(((qr>>2)&1)<<2), identical for both A-rows (pk0, pk0+4);
//   16-lane phase now covers all 8 bank-quads exactly 2x (free) instead of
//   4 quads 4x. Everything else byte-identical to r5.

typedef _Float16 f16;
typedef f16 f16x8 __attribute__((ext_vector_type(8)));
typedef float f32x4 __attribute__((ext_vector_type(4)));

#define NT 64
#define MF32(a, b, c) __builtin_amdgcn_mfma_f32_16x16x32_f16(a, b, c, 0, 0, 0)

__device__ __forceinline__ void gl_lds16(const f16* g, f16* l) {
  __builtin_amdgcn_global_load_lds(
      (const __attribute__((address_space(1))) void*)g,
      (__attribute__((address_space(3))) void*)l, 16, 0, 0);
}

// ---- pre-kernel: build swizzled per-tile images (grid 256 x 256) ----
__global__ void prep_kernel(const float* __restrict__ keys, f16* __restrict__ ws) {
  int i = blockIdx.x * 256 + threadIdx.x;  // 0..65535
  int t = i >> 10;
  {  // Kh image: key kk, chunk c; slot = c ^ ((kk&3)|(((kk>>3)&1)<<2))
    int kk = (i >> 5) & 31, c = i & 31;
    const float* src = keys + (((t << 5) + kk) << 8) + (c << 3);
    f16x8 v;
    #pragma unroll
    for (int e = 0; e < 8; ++e) v[e] = (f16)src[e];
    int xk = (kk & 3) | (((kk >> 3) & 1) << 2);
    *(f16x8*)&ws[t * 8192 + kk * 256 + ((c ^ xk) << 3)] = v;
  }
  {  // KT image: dim d, key-group g (keys g*8..g*8+7 at dim d), swizzled slot
    int d = (i >> 2) & 255, g = i & 3;
    const float* src = keys + (((t << 5) + (g << 3)) << 8) + d;
    f16x8 v;
    #pragma unroll
    for (int j = 0; j < 8; ++j) v[j] = (f16)src[j << 8];
    *(f16x8*)&ws[524288 + t * 8192 + (d >> 1) * 64 +
                 (((((d & 1) << 2) | g) ^ ((d >> 1) & 7)) << 3)] = v;
  }
}

__global__ __launch_bounds__(256, 2)
void mtr_kernel(const f16* __restrict__ ws,
                const float* __restrict__ query,
                float* __restrict__ out) {
  __shared__ f16 KB[2][8192];   // 32 KB: Kh images (dbuf)
  __shared__ f16 KT[2][8192];   // 32 KB: KT images (dbuf)

  const int tid  = threadIdx.x;
  const int lane = tid & 63;
  const int wave = tid >> 6;   // 0..3, owns q-rows [wave*16, wave*16+16)
  const int g    = lane >> 4;  // 0..3
  const int qr   = lane & 15;

  const int nbase  = blockIdx.x * 64;
  const int b      = nbase >> 12;
  const int hwbase = nbase & 4095;

  // ---- q fragments, hi/lo fp16 split (q exact). Score B-layout:
  // lane holds q[row=qr][d = dt*32 + g*8 + j]
  f16x8 qh[8], ql[8];
  {
    const float* qb = query + ((size_t)b << 20) + hwbase + wave * 16 + qr;
    #pragma unroll
    for (int dt = 0; dt < 8; ++dt)
      #pragma unroll
      for (int j = 0; j < 8; ++j) {
        int c = dt * 32 + g * 8 + j;
        float v = qb[(size_t)c << 12];
        f16 h = (f16)v;
        qh[dt][j] = h;
        ql[dt][j] = (f16)(v - (float)h);
      }
  }

  f32x4 O[16];
  #pragma unroll
  for (int i = 0; i < 16; ++i) O[i] = (f32x4){0.f, 0.f, 0.f, 0.f};
  float m_run = -INFINITY, l_run = 0.f;

  // score A-rows: key-permuted phys key = 8*(qr>>2) + 4*kt + (qr&3)
  const int rb0 = (((qr >> 2) << 3) + (qr & 3)) << 8;  // row pk0 (512B rows)
  const int rb1 = rb0 + 1024;                          // pk0 + 4
  const int xs  = (qr & 3) | (((qr >> 2) & 1) << 2);   // image xor, both rows
  // PV read row-base (f16 units) within each dtile's 1KB
  const int rbT = ((qr >> 1) << 6) + (((((qr & 1) << 2) | g) ^ ((qr >> 1) & 7)) << 3);

  // ---- DMA duty: waves 0,1 -> KB halves; waves 2,3 -> KT halves.
  const f16* wsrc = ws + ((wave >> 1) ? 524288 : 0) + ((wave & 1) << 12) + lane * 8;
  const int dst_half = (wave & 1) << 12;  // f16 offset of this wave's half

  // prologue: stage tile 0 into buffer 0
  {
    f16* dstb = ((wave >> 1) ? &KT[0][0] : &KB[0][0]) + dst_half;
    #pragma unroll
    for (int i = 0; i < 8; ++i) gl_lds16(wsrc + i * 512, dstb + i * 512);
  }
  __syncthreads();

  for (int t = 0; t < NT; ++t) {
    const int cur = t & 1;

    // ---- issue next-tile DMA into other buffer (drained by end barrier)
    if (t + 1 < NT) {
      f16* dstb = ((wave >> 1) ? &KT[cur ^ 1][0] : &KB[cur ^ 1][0]) + dst_half;
      const f16* s = wsrc + (t + 1) * 8192;
      #pragma unroll
      for (int i = 0; i < 8; ++i) gl_lds16(s + i * 512, dstb + i * 512);
    }

    // ---- score: S^T[key'][q], key-permuted A-rows, q exact via hi/lo
    const f16* KBc = &KB[cur][0];
    f32x4 s0 = (f32x4){0.f, 0.f, 0.f, 0.f};
    f32x4 s1 = (f32x4){0.f, 0.f, 0.f, 0.f};
    #pragma unroll
    for (int dt = 0; dt < 8; ++dt) {
      int c = (dt << 2) + g;
      f16x8 a0 = *(const f16x8*)&KBc[rb0 + ((c ^ xs) << 3)];
      f16x8 a1 = *(const f16x8*)&KBc[rb1 + ((c ^ xs) << 3)];
      s0 = MF32(a0, qh[dt], s0); s0 = MF32(a0, ql[dt], s0);
      s1 = MF32(a1, qh[dt], s1); s1 = MF32(a1, ql[dt], s1);
    }
    // lane holds S[q=qr][key 8g+i] (s0) and 8g+4+i (s1)

    // ---- online softmax (row = qr); defer-max (T13)
    float tmax = fmaxf(fmaxf(fmaxf(s0[0], s0[1]), fmaxf(s0[2], s0[3])),
                       fmaxf(fmaxf(s1[0], s1[1]), fmaxf(s1[2], s1[3])));
    tmax = fmaxf(tmax, __shfl_xor(tmax, 16));
    tmax = fmaxf(tmax, __shfl_xor(tmax, 32));

    if (__any(tmax > m_run + 8.f)) {
      float m_new = fmaxf(m_run, tmax);
      float sc = __expf(m_run - m_new);
      l_run *= sc;
      m_run = m_new;
      float osc0 = __shfl(sc, g * 4 + 0);
      float osc1 = __shfl(sc, g * 4 + 1);
      float osc2 = __shfl(sc, g * 4 + 2);
      float osc3 = __shfl(sc, g * 4 + 3);
      #pragma unroll
      for (int dtile = 0; dtile < 16; ++dtile) {
        O[dtile][0] *= osc0; O[dtile][1] *= osc1;
        O[dtile][2] *= osc2; O[dtile][3] *= osc3;
      }
    }

    float ts = 0.f;
    f16x8 pa;  // x32 PV A-frag: k = g*8+j -> phys key 8g+j
    #pragma unroll
    for (int i = 0; i < 4; ++i) {
      float e0 = __expf(s0[i] - m_run);
      float e1 = __expf(s1[i] - m_run);
      ts += e0 + e1;
      pa[i] = (f16)e0;
      pa[4 + i] = (f16)e1;
    }
    ts += __shfl_xor(ts, 16);
    ts += __shfl_xor(ts, 32);
    l_run += ts;

    // ---- PV: all-x32, B-frags from KT image (compile-time strides)
    const f16* KTc = &KT[cur][0];
    #pragma unroll
    for (int dtile = 0; dtile < 16; ++dtile) {
      f16x8 vb = *(const f16x8*)&KTc[dtile * 512 + rbT];
      O[dtile] = MF32(pa, vb, O[dtile]);
    }

    __syncthreads();  // next-tile images complete; buffers swap
  }

  // ---- epilogue: normalize by row-sum, store NCHW (float4 over w)
  float n0 = 1.f / __shfl(l_run, g * 4 + 0);
  float n1 = 1.f / __shfl(l_run, g * 4 + 1);
  float n2 = 1.f / __shfl(l_run, g * 4 + 2);
  float n3 = 1.f / __shfl(l_run, g * 4 + 3);
  float* ob = out + ((size_t)b << 20) + hwbase + wave * 16 + g * 4;
  #pragma unroll
  for (int dtile = 0; dtile < 16; ++dtile) {
    int c = dtile * 16 + qr;
    float4 w4;
    w4.x = O[dtile][0] * n0;
    w4.y = O[dtile][1] * n1;
    w4.z = O[dtile][2] * n2;
    w4.w = O[dtile][3] * n3;
    *(float4*)(ob + ((size_t)c << 12)) = w4;
  }
}

extern "C" void kernel_launch(void* const* d_in, const int* in_sizes, int n_in,
                              void* d_out, int out_size, void* d_ws, size_t ws_size,
                              hipStream_t stream) {
  const float* keys  = (const float*)d_in[0];
  const float* query = (const float*)d_in[1];
  float* out = (float*)d_out;
  f16* ws = (f16*)d_ws;
  hipLaunchKernelGGL(prep_kernel, dim3(256), dim3(256), 0, stream, keys, ws);
  hipLaunchKernelGGL(mtr_kernel, dim3(512), dim3(256), 0, stream, ws, query, out);
}